// Round 12
// baseline (240.836 us; speedup 1.0000x reference)
//
#include <hip/hip_runtime.h>
#include <math.h>

#define NUM_TASKS 16
#define B_ROWS    8192
#define P_ROWS    8448             // sorted-row space, each task 16-aligned

typedef __attribute__((ext_vector_type(4))) float f32x4;
typedef __attribute__((ext_vector_type(8))) short bf16x8;
typedef __attribute__((ext_vector_type(4))) short bf16x4;
typedef unsigned short ushort_t;

__device__ __forceinline__ short f2bf(float f) {
    union { float f; unsigned u; } c; c.f = f;
    unsigned u = c.u;
    unsigned r = (u + 0x7FFFu + ((u >> 16) & 1u)) >> 16;
    return (short)r;
}

__device__ __forceinline__ float fast_tanh(float x) {
    float e = __expf(2.0f * x);
    return 1.0f - 2.0f / (e + 1.0f);
}

// ---------------------------------------------------------------------------
// Packed fragment-major layout for x/H/W ([X][K], 16-row groups):
//   elem(x,k;K) = ((x>>4)*(K/8) + (k>>3))*128 + (x&15)*8 + (k&7)
// One MFMA fragment (16 x-rows x 32 k) = 1 KB contiguous; lane l reads 16B at
// (l>>4)*256 + (l&15)*16.  No XOR swizzle (global memory, not LDS).
// ---------------------------------------------------------------------------

// ---------------------------------------------------------------------------
// Bucket: stable counting sort of rows by task; task starts 16-aligned.
// Exports sidx[P_ROWS] (zero-init), pstart[16], tot[16].
// ---------------------------------------------------------------------------
__global__ __launch_bounds__(256) void bucket_kernel(
    const int* __restrict__ task_ids,
    int* __restrict__ sidx,
    int* __restrict__ pstart_g,
    int* __restrict__ tot_g)
{
    __shared__ int cnt[256][NUM_TASKS];
    __shared__ int pstart[NUM_TASKS];
    __shared__ int tot[NUM_TASKS];

    const int tid = threadIdx.x;
    #pragma unroll
    for (int t = 0; t < NUM_TASKS; ++t) cnt[tid][t] = 0;
    const int base = tid * (B_ROWS / 256);

    for (int i = 0; i < B_ROWS / 256; ++i) {
        int t = task_ids[base + i];
        cnt[tid][t]++;
    }
    __syncthreads();

    if (tid < NUM_TASKS) {
        int s = 0;
        for (int c = 0; c < 256; ++c) { int v = cnt[c][tid]; cnt[c][tid] = s; s += v; }
        tot[tid] = s;
    }
    __syncthreads();

    if (tid == 0) {
        int p = 0;
        for (int t = 0; t < NUM_TASKS; ++t) {
            pstart[t] = p;
            p += ((tot[t] + 15) / 16) * 16;
        }
    }
    __syncthreads();

    if (tid < NUM_TASKS) {
        pstart_g[tid] = pstart[tid];
        tot_g[tid]    = tot[tid];
    }

    for (int i = 0; i < P_ROWS / 256; ++i) sidx[tid + i * 256] = 0;
    __syncthreads();

    for (int i = 0; i < B_ROWS / 256; ++i) {
        int row = base + i;
        int t = task_ids[row];
        int pos = pstart[t] + cnt[tid][t];
        cnt[tid][t] = cnt[tid][t] + 1;
        sidx[pos] = row;
    }
}

// ---------------------------------------------------------------------------
// x gather + convert + pack: xs = packed(x[sidx[pos]]), K=512. 4 rows/block.
// ---------------------------------------------------------------------------
__global__ __launch_bounds__(256) void xconv(
    const float* __restrict__ x,
    const int* __restrict__ sidx,
    ushort_t* __restrict__ xs)
{
    const int tid  = threadIdx.x;
    const int pos  = blockIdx.x * 4 + (tid >> 6);
    const int lane = tid & 63;
    const int src  = sidx[pos];
    const float* sp = x + (size_t)src * 512 + lane * 8;
    f32x4 v0 = *(const f32x4*)sp;
    f32x4 v1 = *(const f32x4*)(sp + 4);
    bf16x8 pk;
    pk[0] = f2bf(v0[0]); pk[1] = f2bf(v0[1]);
    pk[2] = f2bf(v0[2]); pk[3] = f2bf(v0[3]);
    pk[4] = f2bf(v1[0]); pk[5] = f2bf(v1[1]);
    pk[6] = f2bf(v1[2]); pk[7] = f2bf(v1[3]);
    ushort_t* dp = xs + ((size_t)(pos >> 4) * 64 + lane) * 128 + (pos & 15) * 8;
    *(bf16x8*)dp = pk;
}

// ---------------------------------------------------------------------------
// Weight convert + transpose + pack: W[t][k][n] fp32 -> packed [t][n][k] bf16
// (fragment-major; verified R6).
// ---------------------------------------------------------------------------
template<int K, int N>
__global__ __launch_bounds__(256) void wconv(
    const float* __restrict__ W, ushort_t* __restrict__ Wt)
{
    const int t  = blockIdx.z;
    const int kb = blockIdx.y * 64;
    const int nb = blockIdx.x * 64;
    const float* src = W + (size_t)t * K * N;
    ushort_t* dst = Wt + (size_t)t * N * K;

    __shared__ ushort_t tile[64][68];

    const int tid = threadIdx.x;
    {
        int kl  = tid >> 4;
        int nl4 = (tid & 15) * 4;
        #pragma unroll
        for (int r = 0; r < 4; ++r) {
            int k = kl + r * 16;
            f32x4 v = *(const f32x4*)(src + (size_t)(kb + k) * N + nb + nl4);
            tile[nl4 + 0][k] = (ushort_t)f2bf(v[0]);
            tile[nl4 + 1][k] = (ushort_t)f2bf(v[1]);
            tile[nl4 + 2][k] = (ushort_t)f2bf(v[2]);
            tile[nl4 + 3][k] = (ushort_t)f2bf(v[3]);
        }
    }
    __syncthreads();
    {
        int nl = tid >> 2;
        int c  = (tid & 3) * 16;
        int n  = nb + nl;
        int k0 = kb + c;
        bf16x4 v0 = *(const bf16x4*)&tile[nl][c + 0];
        bf16x4 v1 = *(const bf16x4*)&tile[nl][c + 4];
        bf16x4 v2 = *(const bf16x4*)&tile[nl][c + 8];
        bf16x4 v3 = *(const bf16x4*)&tile[nl][c + 12];
        ushort_t* dg = dst + ((size_t)(n >> 4) * (K / 8) + (k0 >> 3)) * 128
                           + (n & 15) * 8;
        *(bf16x4*)(dg + 0)   = v0;
        *(bf16x4*)(dg + 4)   = v1;
        *(bf16x4*)(dg + 128) = v2;
        *(bf16x4*)(dg + 132) = v3;
    }
}

// ---------------------------------------------------------------------------
// Per-task N-sliced GEMM: block = (task, 64-col slice); W read exactly ONCE
// per layer (slices partition N). 512 thr = 8 waves; wave = 4 m-frags x
// 4 n-frags; loops over ALL task rows in 512-row chunks. No LDS, no barriers:
// A-frags (1KB contiguous) and W-frags (1KB, L1-shared x8 waves) stream
// global->VGPR with depth-2 prefetch. Task->XCD pinned via blockIdx%8 so
// the task's A/H rows (~1-2 MB) stay L2-resident.
//   FINAL=0: H-write bf16 packed (width 1024); FINAL=1: fp32 scatter via sidx.
// ---------------------------------------------------------------------------
template<int K, int N, int SLICES, int FINAL>
__global__ __launch_bounds__(512, 1) void task_gemm(
    const ushort_t* __restrict__ A,      // packed, P_ROWS x K
    const ushort_t* __restrict__ Wt,     // packed [T][N][K]
    const float* __restrict__ bias,      // [T][N]
    void* __restrict__ outp,             // H (packed bf16, width 1024) or out
    const int* __restrict__ sidx,
    const int* __restrict__ pstart_g,
    const int* __restrict__ tot_g)
{
    constexpr int NS = K / 32;

    const int b     = blockIdx.x;
    const int j     = b >> 3;
    const int task  = (b & 7) * 2 + (j & 1);   // XCD b%8 hosts tasks 2*xcd, 2*xcd+1
    const int slice = j >> 1;
    const int n0    = slice * 64;

    const int rows   = tot_g[task];
    const int gbase  = pstart_g[task] >> 4;
    const int nfrags = (rows + 15) >> 4;

    const int tid  = threadIdx.x;
    const int lane = tid & 63;
    const int wid  = tid >> 6;
    const int q    = lane >> 4;
    const int m15  = lane & 15;
    const int loff = q * 256 + m15 * 16;

    const char* Wp[4];
    #pragma unroll
    for (int nf = 0; nf < 4; ++nf)
        Wp[nf] = (const char*)(Wt + (size_t)task * N * K)
               + ((size_t)(n0 / 16 + nf) * (K / 8)) * 256 + loff;

    for (int cf = 0; cf < nfrags; cf += 32) {
        const int myf = cf + wid * 4;
        if (myf >= nfrags) break;           // no barriers -> per-wave early-out

        const char* Ap[4];
        #pragma unroll
        for (int mf = 0; mf < 4; ++mf) {
            int gl = myf + mf;
            int gc = (gl < nfrags) ? gl : 0;
            Ap[mf] = (const char*)A + ((size_t)(gbase + gc) * (K / 8)) * 256 + loff;
        }

        f32x4 acc[4][4];
        #pragma unroll
        for (int mf = 0; mf < 4; ++mf)
            #pragma unroll
            for (int nf = 0; nf < 4; ++nf)
                acc[mf][nf] = (f32x4){0.f, 0.f, 0.f, 0.f};

        bf16x8 a[2][4], w[2][4];
        #pragma unroll
        for (int mf = 0; mf < 4; ++mf) a[0][mf] = *(const bf16x8*)(Ap[mf]);
        #pragma unroll
        for (int nf = 0; nf < 4; ++nf) w[0][nf] = *(const bf16x8*)(Wp[nf]);

        #pragma unroll
        for (int s = 0; s < NS; ++s) {
            const int cur = s & 1;
            if (s + 1 < NS) {
                const size_t ko = (size_t)(s + 1) * 1024;
                #pragma unroll
                for (int mf = 0; mf < 4; ++mf)
                    a[cur ^ 1][mf] = *(const bf16x8*)(Ap[mf] + ko);
                #pragma unroll
                for (int nf = 0; nf < 4; ++nf)
                    w[cur ^ 1][nf] = *(const bf16x8*)(Wp[nf] + ko);
            }
            __builtin_amdgcn_s_setprio(1);
            #pragma unroll
            for (int mf = 0; mf < 4; ++mf)
                #pragma unroll
                for (int nf = 0; nf < 4; ++nf)
                    acc[mf][nf] = __builtin_amdgcn_mfma_f32_16x16x32_bf16(
                        w[cur][nf], a[cur][mf], acc[mf][nf], 0, 0, 0);
            __builtin_amdgcn_s_setprio(0);
        }

        // ---- epilogue for this chunk ----
        #pragma unroll
        for (int mf = 0; mf < 4; ++mf) {
            const int gl = myf + mf;
            if (gl >= nfrags) continue;     // wave-uniform
            if (!FINAL) {
                #pragma unroll
                for (int nf = 0; nf < 4; ++nf) {
                    const int n_lo = n0 + nf * 16 + q * 4;
                    const f32x4 bb = *(const f32x4*)(bias + (size_t)task * N + n_lo);
                    bf16x4 pk;
                    #pragma unroll
                    for (int r = 0; r < 4; ++r)
                        pk[r] = f2bf(fast_tanh(acc[mf][nf][r] + bb[r]));
                    // packed H, width 1024 (pad rows written harmlessly)
                    char* dp = (char*)outp
                        + ((size_t)(gbase + gl) * 128 + (n_lo >> 3)) * 256
                        + m15 * 16 + (n_lo & 7) * 2;
                    *(bf16x4*)dp = pk;
                }
            } else {
                const int rit = gl * 16 + m15;      // row index within task
                if (rit < rows) {
                    const int orow = sidx[(gbase + gl) * 16 + m15];
                    #pragma unroll
                    for (int nf = 0; nf < 4; ++nf) {
                        const int n_lo = n0 + nf * 16 + q * 4;
                        const f32x4 bb = *(const f32x4*)(bias + (size_t)task * N + n_lo);
                        f32x4 v;
                        #pragma unroll
                        for (int r = 0; r < 4; ++r)
                            v[r] = acc[mf][nf][r] + bb[r];
                        *(f32x4*)((float*)outp + (size_t)orow * 256 + n_lo) = v;
                    }
                }
            }
        }
    }
}

// ---------------------------------------------------------------------------
extern "C" void kernel_launch(void* const* d_in, const int* in_sizes, int n_in,
                              void* d_out, int out_size, void* d_ws, size_t ws_size,
                              hipStream_t stream)
{
    const float* x        = (const float*)d_in[0];
    const int*   task_ids = (const int*)  d_in[1];
    const float* k0       = (const float*)d_in[2];
    const float* b0       = (const float*)d_in[3];
    const float* k1       = (const float*)d_in[4];
    const float* b1       = (const float*)d_in[5];
    const float* k2       = (const float*)d_in[6];
    const float* b2       = (const float*)d_in[7];
    float* out = (float*)d_out;

    char* ws = (char*)d_ws;
    int* sidx     = (int*)ws;                 // P_ROWS ints
    int* pstart_g = sidx + P_ROWS;
    int* tot_g    = pstart_g + 16;

    size_t off = 65536;
    ushort_t* xs  = (ushort_t*)(ws + off); off += (size_t)P_ROWS * 512 * 2;
    ushort_t* H0  = (ushort_t*)(ws + off); off += (size_t)P_ROWS * 1024 * 2;
    ushort_t* H1  = (ushort_t*)(ws + off); off += (size_t)P_ROWS * 1024 * 2;
    ushort_t* Wt0 = (ushort_t*)(ws + off); off += (size_t)16 * 512 * 1024 * 2;
    ushort_t* Wt1 = (ushort_t*)(ws + off); off += (size_t)16 * 1024 * 1024 * 2;
    ushort_t* Wt2 = (ushort_t*)(ws + off); off += (size_t)16 * 1024 * 256 * 2;

    bucket_kernel<<<1, 256, 0, stream>>>(task_ids, sidx, pstart_g, tot_g);
    xconv<<<P_ROWS / 4, 256, 0, stream>>>(x, sidx, xs);
    wconv< 512, 1024><<<dim3(16,  8, 16), 256, 0, stream>>>(k0, Wt0);
    wconv<1024, 1024><<<dim3(16, 16, 16), 256, 0, stream>>>(k1, Wt1);
    wconv<1024,  256><<<dim3( 4, 16, 16), 256, 0, stream>>>(k2, Wt2);

    // L0: xs[.,512] x W0 -> H0[.,1024] ; 16 slices x 16 tasks = 256 blocks
    task_gemm< 512, 1024, 16, 0><<<256, 512, 0, stream>>>(
        xs, Wt0, b0, H0, sidx, pstart_g, tot_g);
    // L1: H0 x W1 -> H1[.,1024]
    task_gemm<1024, 1024, 16, 0><<<256, 512, 0, stream>>>(
        H0, Wt1, b1, H1, sidx, pstart_g, tot_g);
    // L2: H1 x W2 -> out[.,256] fp32 scatter ; 4 slices x 16 tasks = 64 blocks
    task_gemm<1024,  256,  4, 1><<<64, 512, 0, stream>>>(
        H1, Wt2, b2, out, sidx, pstart_g, tot_g);
}

// Round 13
// 113.824 us; speedup vs baseline: 2.1159x; 2.1159x over previous
//
#include <hip/hip_runtime.h>
#include <math.h>

#define NUM_TASKS 16
#define B_ROWS    8192
#define TROWS     48               // rows per fused tile (3 x 16)
#define NB_FUSED  186              // max tiles: floor(8192/48) + 16
#define P_ROWS    8960             // padded sorted-row space (tasks 48-aligned)

typedef __attribute__((ext_vector_type(4))) float f32x4;
typedef __attribute__((ext_vector_type(8))) short bf16x8;
typedef __attribute__((ext_vector_type(4))) short bf16x4;
typedef unsigned short ushort_t;

__device__ __forceinline__ short f2bf(float f) {
    union { float f; unsigned u; } c; c.f = f;
    unsigned u = c.u;
    unsigned r = (u + 0x7FFFu + ((u >> 16) & 1u)) >> 16;
    return (short)r;
}

__device__ __forceinline__ float fast_tanh(float x) {
    float e = __expf(2.0f * x);
    return 1.0f - 2.0f / (e + 1.0f);
}

// ---------------------------------------------------------------------------
// W layout (per task): 32-col x 32-k granules of 2 KB, k-minor:
//   granule(n,k) = (n>>5)*(K/32) + (k>>5); within granule:
//   byte = ((n>>4)&1)*1024 + ((k>>3)&3)*256 + (n&15)*16 + (k&7)*2
// A wave owning cols [wid*64, wid*64+64) reads granules wid*2*(K/32) ..
// (wid+1)*2*(K/32) as ONE contiguous stream, 2 KB per k32-step.
// H (LDS): 16-row groups, XOR slot swizzle ((m&15)^(kg&7)) — conflict-free.
// ---------------------------------------------------------------------------

// ---------------------------------------------------------------------------
// Bucket kernel: stable counting sort of rows by task, tasks padded to 48.
// ---------------------------------------------------------------------------
__global__ __launch_bounds__(256) void bucket_kernel(
    const int* __restrict__ task_ids,
    int* __restrict__ sidx,
    int* __restrict__ tile_base,
    int* __restrict__ tile_task,
    int* __restrict__ tile_end,
    int* __restrict__ ntiles)
{
    __shared__ int cnt[256][NUM_TASKS];
    __shared__ int pstart[NUM_TASKS];
    __shared__ int tot[NUM_TASKS];

    const int tid = threadIdx.x;
    #pragma unroll
    for (int t = 0; t < NUM_TASKS; ++t) cnt[tid][t] = 0;
    const int base = tid * (B_ROWS / 256);

    for (int i = 0; i < B_ROWS / 256; ++i) {
        int t = task_ids[base + i];
        cnt[tid][t]++;
    }
    __syncthreads();

    if (tid < NUM_TASKS) {
        int s = 0;
        for (int c = 0; c < 256; ++c) { int v = cnt[c][tid]; cnt[c][tid] = s; s += v; }
        tot[tid] = s;
    }
    __syncthreads();

    if (tid == 0) {
        int p = 0, nt = 0;
        for (int t = 0; t < NUM_TASKS; ++t) {
            pstart[t] = p;
            for (int r = 0; r < tot[t]; r += TROWS) {
                tile_base[nt] = p + r;
                tile_task[nt] = t;
                tile_end[nt]  = p + tot[t];
                nt++;
            }
            p += ((tot[t] + TROWS - 1) / TROWS) * TROWS;
        }
        *ntiles = nt;
    }
    __syncthreads();

    for (int i = 0; i < P_ROWS / 256; ++i) sidx[tid + i * 256] = 0;
    __syncthreads();

    for (int i = 0; i < B_ROWS / 256; ++i) {
        int row = base + i;
        int t = task_ids[row];
        int pos = pstart[t] + cnt[tid][t];
        cnt[tid][t] = cnt[tid][t] + 1;
        sidx[pos] = row;
    }
}

// ---------------------------------------------------------------------------
// Weight convert + transpose + pack into 32x32 granule layout.
// ---------------------------------------------------------------------------
template<int K, int N>
__global__ __launch_bounds__(256) void wconv(
    const float* __restrict__ W, ushort_t* __restrict__ Wt)
{
    const int t  = blockIdx.z;
    const int kb = blockIdx.y * 64;
    const int nb = blockIdx.x * 64;
    const float* src = W + (size_t)t * K * N;
    ushort_t* dst = Wt + (size_t)t * N * K;

    __shared__ ushort_t tile[64][68];

    const int tid = threadIdx.x;
    {
        int kl  = tid >> 4;
        int nl4 = (tid & 15) * 4;
        #pragma unroll
        for (int r = 0; r < 4; ++r) {
            int k = kl + r * 16;
            f32x4 v = *(const f32x4*)(src + (size_t)(kb + k) * N + nb + nl4);
            tile[nl4 + 0][k] = (ushort_t)f2bf(v[0]);
            tile[nl4 + 1][k] = (ushort_t)f2bf(v[1]);
            tile[nl4 + 2][k] = (ushort_t)f2bf(v[2]);
            tile[nl4 + 3][k] = (ushort_t)f2bf(v[3]);
        }
    }
    __syncthreads();
    {
        int nl = tid >> 2;            // 0..63 local n
        int c  = (tid & 3) * 16;      // local k chunk of 16
        int n  = nb + nl;
        int k0 = kb + c;
        bf16x4 v0 = *(const bf16x4*)&tile[nl][c + 0];
        bf16x4 v1 = *(const bf16x4*)&tile[nl][c + 4];
        bf16x4 v2 = *(const bf16x4*)&tile[nl][c + 8];
        bf16x4 v3 = *(const bf16x4*)&tile[nl][c + 12];
        // granule layout (ushort units): granule*1024 + frag*512 + sub*128
        ushort_t* dg = dst
            + ((size_t)(n >> 5) * (K / 32) + (k0 >> 5)) * 1024
            + ((n >> 4) & 1) * 512
            + ((k0 >> 3) & 3) * 128 + (n & 15) * 8;
        *(bf16x4*)(dg + 0)   = v0;
        *(bf16x4*)(dg + 4)   = v1;
        *(bf16x4*)(dg + 128) = v2;
        *(bf16x4*)(dg + 132) = v3;
    }
}

// ---------------------------------------------------------------------------
// Hidden layer (16 waves): wave owns 64 cols = 2 chunks x 2 frags. Contiguous
// W stream (2 KB/step), depth-4 slot pipeline with unconditional reissue
// (buffer pad absorbs over-run). acc[2][3][2]=48 + wreg[4][2]=32 + h[3]=12
// regs -> fits 128-reg budget at 4 waves/SIMD. No barriers inside K-loop.
// ---------------------------------------------------------------------------
template<int K, int NNOUT, int INPLACE>
__device__ __forceinline__ void hidden_layer(
    const char* __restrict__ Hin,
    char* __restrict__ Hout,
    const ushort_t* __restrict__ Wt,      // task's packed weights
    const float* __restrict__ bias,       // task's bias
    int lane, int wid)
{
    constexpr int NS = K / 32;
    constexpr int G  = 2 * NS;            // granules per wave stream

    const int q   = lane >> 4;
    const int m15 = lane & 15;

    const char* pw = (const char*)Wt + (size_t)wid * G * 2048
                   + q * 256 + m15 * 16;

    f32x4 acc[2][3][2];
    #pragma unroll
    for (int c = 0; c < 2; ++c)
        #pragma unroll
        for (int mf = 0; mf < 3; ++mf)
            #pragma unroll
            for (int nf = 0; nf < 2; ++nf)
                acc[c][mf][nf] = (f32x4){0.f, 0.f, 0.f, 0.f};

    bf16x8 wreg[4][2];
    #pragma unroll
    for (int b = 0; b < 4; ++b) {
        wreg[b][0] = *(const bf16x8*)(pw);
        wreg[b][1] = *(const bf16x8*)(pw + 1024);
        pw += 2048;
    }

    #pragma unroll
    for (int g = 0; g < G; ++g) {
        const int c  = g / NS;            // static (unrolled)
        const int s  = g % NS;
        const int kg = s * 4 + q;
        bf16x8 h[3];
        #pragma unroll
        for (int mf = 0; mf < 3; ++mf)
            h[mf] = *(const bf16x8*)(Hin
                        + ((size_t)(mf * (K / 8) + kg) * 256)
                        + ((m15 ^ (kg & 7)) * 16));
        __builtin_amdgcn_s_setprio(1);
        #pragma unroll
        for (int mf = 0; mf < 3; ++mf)
            #pragma unroll
            for (int nf = 0; nf < 2; ++nf)
                acc[c][mf][nf] = __builtin_amdgcn_mfma_f32_16x16x32_bf16(
                    wreg[g & 3][nf], h[mf], acc[c][mf][nf], 0, 0, 0);
        __builtin_amdgcn_s_setprio(0);
        // unconditional reissue; final 4 granules over-run into buffer pad
        wreg[g & 3][0] = *(const bf16x8*)(pw);
        wreg[g & 3][1] = *(const bf16x8*)(pw + 1024);
        pw += 2048;
    }

    if (INPLACE) __syncthreads();         // all waves done reading H_in
    #pragma unroll
    for (int c = 0; c < 2; ++c) {
        #pragma unroll
        for (int mf = 0; mf < 3; ++mf) {
            #pragma unroll
            for (int nf = 0; nf < 2; ++nf) {
                const int n_lo = (wid * 2 + c) * 32 + nf * 16 + q * 4;
                const f32x4 bb = *(const f32x4*)(bias + n_lo);
                bf16x4 pk;
                #pragma unroll
                for (int r = 0; r < 4; ++r)
                    pk[r] = f2bf(fast_tanh(acc[c][mf][nf][r] + bb[r]));
                const int kg2 = n_lo >> 3;
                size_t off = ((size_t)(mf * (NNOUT / 8) + kg2) * 256)
                           + ((m15 ^ (kg2 & 7)) * 16) + (n_lo & 7) * 2;
                *(bf16x4*)(Hout + off) = pk;
            }
        }
    }
    __syncthreads();                      // H_out complete
}

// ---------------------------------------------------------------------------
// Final layer (N=256): wave owns 16 cols = 1 frag (wave pairs share a 32-col
// granule block). 1 KB/step stream, depth-4 pipeline. fp32 scatter via sidx.
// ---------------------------------------------------------------------------
template<int K>
__device__ __forceinline__ void final_layer(
    const char* __restrict__ Hin,
    const ushort_t* __restrict__ Wt,
    const float* __restrict__ bias,
    float* __restrict__ outp,
    const int* __restrict__ sidx,
    int rowbase, int rowend, int lane, int wid)
{
    constexpr int NS = K / 32;

    const int q   = lane >> 4;
    const int m15 = lane & 15;

    const char* pw = (const char*)Wt + (size_t)(wid >> 1) * NS * 2048
                   + (wid & 1) * 1024 + q * 256 + m15 * 16;

    f32x4 acc[3];
    #pragma unroll
    for (int mf = 0; mf < 3; ++mf) acc[mf] = (f32x4){0.f, 0.f, 0.f, 0.f};

    bf16x8 wreg[4];
    #pragma unroll
    for (int b = 0; b < 4; ++b) { wreg[b] = *(const bf16x8*)(pw); pw += 2048; }

    #pragma unroll
    for (int s = 0; s < NS; ++s) {
        const int kg = s * 4 + q;
        bf16x8 h[3];
        #pragma unroll
        for (int mf = 0; mf < 3; ++mf)
            h[mf] = *(const bf16x8*)(Hin
                        + ((size_t)(mf * (K / 8) + kg) * 256)
                        + ((m15 ^ (kg & 7)) * 16));
        __builtin_amdgcn_s_setprio(1);
        #pragma unroll
        for (int mf = 0; mf < 3; ++mf)
            acc[mf] = __builtin_amdgcn_mfma_f32_16x16x32_bf16(
                wreg[s & 3], h[mf], acc[mf], 0, 0, 0);
        __builtin_amdgcn_s_setprio(0);
        wreg[s & 3] = *(const bf16x8*)(pw);
        pw += 2048;
    }

    const int n_lo = (wid >> 1) * 32 + (wid & 1) * 16 + q * 4;
    const f32x4 bb = *(const f32x4*)(bias + n_lo);
    #pragma unroll
    for (int mf = 0; mf < 3; ++mf) {
        const int grow = rowbase + mf * 16 + m15;
        if (grow < rowend) {
            const int orow = sidx[grow];
            f32x4 v;
            #pragma unroll
            for (int r = 0; r < 4; ++r) v[r] = acc[mf][r] + bb[r];
            *(f32x4*)(outp + (size_t)orow * 256 + n_lo) = v;
        }
    }
}

// ---------------------------------------------------------------------------
// Fused 3-layer MLP: one 1024-thread (16-wave) block per 48-row tile.
// LDS 96 KB: H (48x1024 bf16 packed); X (48 KB) overlaid at offset 0.
// ---------------------------------------------------------------------------
__global__ __launch_bounds__(1024, 4) void fused_mlp(
    const float* __restrict__ x,
    const ushort_t* __restrict__ Wt0,
    const ushort_t* __restrict__ Wt1,
    const ushort_t* __restrict__ Wt2,
    const float* __restrict__ b0,
    const float* __restrict__ b1,
    const float* __restrict__ b2,
    float* __restrict__ out,
    const int* __restrict__ sidx,
    const int* __restrict__ tile_base,
    const int* __restrict__ tile_task,
    const int* __restrict__ tile_end,
    const int* __restrict__ ntiles)
{
    __shared__ __align__(16) char lds[98304];

    // bijective XCD mapping (m204): 186 = 8*23 + 2
    const int orig = blockIdx.x;
    constexpr int q8 = NB_FUSED / 8, r8 = NB_FUSED % 8;
    const int xcd = orig & 7, idx = orig >> 3;
    const int tile = (xcd < r8 ? xcd * (q8 + 1) : r8 * (q8 + 1) + (xcd - r8) * q8) + idx;

    if (tile >= *ntiles) return;
    const int rowbase = tile_base[tile];
    const int task    = tile_task[tile];
    const int rowend  = tile_end[tile];

    const int tid  = threadIdx.x;
    const int lane = tid & 63;
    const int wid  = tid >> 6;        // 0..15

    // ---- gather + convert x tile (48 rows x 512 fp32) into packed LDS ----
    #pragma unroll
    for (int i = 0; i < 3; ++i) {
        const int row = wid + i * 16;
        const int src = sidx[rowbase + row];
        const float* sp = x + (size_t)src * 512 + lane * 8;
        f32x4 v0 = *(const f32x4*)sp;
        f32x4 v1 = *(const f32x4*)(sp + 4);
        bf16x8 pk;
        pk[0] = f2bf(v0[0]); pk[1] = f2bf(v0[1]);
        pk[2] = f2bf(v0[2]); pk[3] = f2bf(v0[3]);
        pk[4] = f2bf(v1[0]); pk[5] = f2bf(v1[1]);
        pk[6] = f2bf(v1[2]); pk[7] = f2bf(v1[3]);
        size_t off = ((size_t)((row >> 4) * 64 + lane) * 256)
                   + (((row & 15) ^ (lane & 7)) * 16);
        *(bf16x8*)(lds + off) = pk;
    }
    __syncthreads();

    hidden_layer< 512, 1024, 1>(lds, lds, Wt0 + (size_t)task * 512 * 1024,
                                b0 + task * 1024, lane, wid);
    hidden_layer<1024, 1024, 1>(lds, lds, Wt1 + (size_t)task * 1024 * 1024,
                                b1 + task * 1024, lane, wid);
    final_layer<1024>(lds, Wt2 + (size_t)task * 1024 * 256,
                      b2 + task * 256, out, sidx, rowbase, rowend, lane, wid);
}

// ---------------------------------------------------------------------------
extern "C" void kernel_launch(void* const* d_in, const int* in_sizes, int n_in,
                              void* d_out, int out_size, void* d_ws, size_t ws_size,
                              hipStream_t stream)
{
    const float* x        = (const float*)d_in[0];
    const int*   task_ids = (const int*)  d_in[1];
    const float* k0       = (const float*)d_in[2];
    const float* b0       = (const float*)d_in[3];
    const float* k1       = (const float*)d_in[4];
    const float* b1       = (const float*)d_in[5];
    const float* k2       = (const float*)d_in[6];
    const float* b2       = (const float*)d_in[7];
    float* out = (float*)d_out;

    char* ws = (char*)d_ws;
    int* sidx      = (int*)ws;                    // P_ROWS ints
    int* tile_base = sidx + P_ROWS;
    int* tile_task = tile_base + 512;
    int* tile_end  = tile_task + 512;
    int* ntiles    = tile_end + 512;

    size_t off = 131072;
    // +16 KB pad per W buffer: depth-4 unconditional reissue over-runs
    ushort_t* Wt0 = (ushort_t*)(ws + off); off += (size_t)16 * 512 * 1024 * 2 + 16384;
    ushort_t* Wt1 = (ushort_t*)(ws + off); off += (size_t)16 * 1024 * 1024 * 2 + 16384;
    ushort_t* Wt2 = (ushort_t*)(ws + off); off += (size_t)16 * 1024 * 256 * 2 + 16384;

    bucket_kernel<<<1, 256, 0, stream>>>(task_ids, sidx, tile_base, tile_task,
                                         tile_end, ntiles);
    wconv< 512, 1024><<<dim3(16,  8, 16), 256, 0, stream>>>(k0, Wt0);
    wconv<1024, 1024><<<dim3(16, 16, 16), 256, 0, stream>>>(k1, Wt1);
    wconv<1024,  256><<<dim3( 4, 16, 16), 256, 0, stream>>>(k2, Wt2);

    fused_mlp<<<NB_FUSED, 1024, 0, stream>>>(
        x, Wt0, Wt1, Wt2, b0, b1, b2, out,
        sidx, tile_base, tile_task, tile_end, ntiles);
}